// Round 8
// baseline (316.383 us; speedup 1.0000x reference)
//
#include <hip/hip_runtime.h>
#include <hip/hip_bf16.h>
#include <math.h>

#define NEG_SLOPE 0.2f
#define MAXDEG 64

typedef __attribute__((ext_vector_type(8))) __bf16 bf16x8;
typedef __attribute__((ext_vector_type(4))) float f32x4;

// ---------------- helpers ----------------
__device__ inline float lrelu(float v) { return v > 0.f ? v : NEG_SLOPE * v; }

__device__ inline unsigned short f2bf(float f) {
    __hip_bfloat16 h = __float2bfloat16(f);
    return *reinterpret_cast<unsigned short*>(&h);
}
__device__ inline float bf_lo(unsigned u) { return __uint_as_float(u << 16); }
__device__ inline float bf_hi(unsigned u) { return __uint_as_float(u & 0xffff0000u); }

__device__ inline void gld16(const unsigned short* gp, unsigned short* lp) {
    __builtin_amdgcn_global_load_lds(
        (const __attribute__((address_space(1))) void*)gp,
        (__attribute__((address_space(3))) void*)lp, 16, 0, 0);
}

__device__ inline void transpose_one(const float* __restrict__ in,
                                     unsigned short* __restrict__ out,
                                     int K, int N, int idx) {
    if (idx >= K * N) return;
    int n = idx / K, k = idx % K;
    out[(size_t)n * K + k] = f2bf(in[(size_t)k * N + n]);
}

// ---- raw sync primitives (no vmcnt(0) drain like __syncthreads) ----
#define BARRIER()    asm volatile("s_barrier" ::: "memory")
#define WAIT_LGKM0() asm volatile("s_waitcnt lgkmcnt(0)" ::: "memory")
#define WAIT_VM0()   asm volatile("s_waitcnt vmcnt(0)" ::: "memory")
#define WAIT_VM3()   asm volatile("s_waitcnt vmcnt(3)" ::: "memory")
#define WAIT_VM6()   asm volatile("s_waitcnt vmcnt(6)" ::: "memory")

// -------- fused preprocessing: x-cast + 4 transposes + padded-CSR scatter ----------
__global__ __launch_bounds__(256) void preproc_kernel(
    const float* __restrict__ x, unsigned short* __restrict__ xbf, int n4,
    const float* __restrict__ W1, unsigned short* __restrict__ W1t,
    const float* __restrict__ W2, unsigned short* __restrict__ W2t,
    const float* __restrict__ W3, unsigned short* __restrict__ W3t,
    const float* __restrict__ Ws1, unsigned short* __restrict__ Ws1t,
    const int* __restrict__ ei, int E, int N,
    int* __restrict__ cursor, int* __restrict__ csr,
    int c0, int c1, int c2, int c3, int c4,
    int D, int HC, int C) {
    int b = blockIdx.x;
    int t = threadIdx.x;
    if (b < c0) {                                   // x fp32 -> bf16 (float4)
        int i = b * 256 + t;
        if (i < n4) {
            float4 v = reinterpret_cast<const float4*>(x)[i];
            ushort4 o;
            o.x = f2bf(v.x); o.y = f2bf(v.y); o.z = f2bf(v.z); o.w = f2bf(v.w);
            reinterpret_cast<ushort4*>(xbf)[i] = o;
        }
        return;
    }
    b -= c0;
    if (b < c1) { transpose_one(W1, W1t, D, HC, b * 256 + t); return; }
    b -= c1;
    if (b < c2) { transpose_one(W2, W2t, HC, HC, b * 256 + t); return; }
    b -= c2;
    if (b < c3) { transpose_one(W3, W3t, HC, C, b * 256 + t); return; }
    b -= c3;
    if (b < c4) { transpose_one(Ws1, Ws1t, 128, 64, b * 256 + t); return; }
    b -= c4;
    {                                               // direct padded-CSR scatter
        int e = b * 256 + t;
        if (e < E + N) {
            int src, dst;
            if (e < E) { src = ei[e]; dst = ei[E + e]; }
            else       { src = dst = e - E; }
            int pos = atomicAdd(&cursor[dst], 1);
            if (pos < MAXDEG) csr[dst * MAXDEG + pos] = src;
        }
    }
}

// ---------------- bf16 MFMA GEMM (BM=128, BN=256, BK=32), 8 waves, 3-stage ---------
template <int HEADS>
__global__ __launch_bounds__(512) void gemm_big(const unsigned short* __restrict__ A,
                                                const unsigned short* __restrict__ Bt,
                                                unsigned short* __restrict__ Cc,
                                                int M, int N, int K, int rowTiles,
                                                const float* __restrict__ a_src,
                                                const float* __restrict__ a_dst,
                                                float* __restrict__ alS,
                                                float* __restrict__ alD) {
    __shared__ unsigned short Asl[3][128 * 32];   // 3 x 8 KB
    __shared__ unsigned short Bsl[3][256 * 32];   // 3 x 16 KB
    const int tid  = threadIdx.x;
    const int lane = tid & 63;
    const int wave = tid >> 6;

    int r, c;
    {
        int b = blockIdx.x;
        int mainRows = rowTiles & ~7;
        int mainBlocks = mainRows * 2;
        if (b < mainBlocks) {
            int xcd = b & 7;
            c = (b >> 3) & 1;
            r = (b >> 4) * 8 + xcd;
        } else {
            int idx = b - mainBlocks;
            r = mainRows + (idx >> 1);
            c = idx & 1;
        }
    }
    const int rowBase = r * 128;
    const int colBase = c * 256;
    const int wm = (wave & 1) * 64;        // 8 waves = 2 (m) x 4 (n)
    const int wn = (wave >> 1) * 64;
    const int q   = lane >> 4;
    const int l16 = lane & 15;

    const int ar  = tid >> 2;                       // A row 0..127
    const int acg = (tid & 3) ^ ((ar >> 1) & 3);
    int gaA = rowBase + ar; if (gaA >= M) gaA = M - 1;
    const unsigned short* gpA0 = A + (size_t)gaA * K + acg * 8;

    const int br0  = tid >> 2;                      // B rows 0..127
    const int bcg0 = (tid & 3) ^ ((br0 >> 1) & 3);
    const int br1  = (tid + 512) >> 2;              // B rows 128..255
    const int bcg1 = (tid & 3) ^ ((br1 >> 1) & 3);
    const unsigned short* gpB0 = Bt + (size_t)(colBase + br0) * K + bcg0 * 8;
    const unsigned short* gpB1 = Bt + (size_t)(colBase + br1) * K + bcg1 * 8;

    const int nk = K >> 5;                          // 24 (K=768) or 16 (K=512)
    f32x4 acc[4][4] = {};

    auto stage = [&](int kt, int buf) {
        gld16(gpA0 + kt * 32, &Asl[buf][tid * 8]);
        gld16(gpB0 + kt * 32, &Bsl[buf][tid * 8]);
        gld16(gpB1 + kt * 32, &Bsl[buf][(size_t)(tid + 512) * 8]);
    };
    auto compute = [&](int buf) {
        bf16x8 af[4], bfv[4];
#pragma unroll
        for (int mi = 0; mi < 4; mi++) {
            int row = wm + mi * 16 + l16;
            int ch = q ^ ((row >> 1) & 3);
            af[mi] = *reinterpret_cast<const bf16x8*>(&Asl[buf][row * 32 + ch * 8]);
        }
#pragma unroll
        for (int ni = 0; ni < 4; ni++) {
            int row = wn + ni * 16 + l16;
            int ch = q ^ ((row >> 1) & 3);
            bfv[ni] = *reinterpret_cast<const bf16x8*>(&Bsl[buf][row * 32 + ch * 8]);
        }
#pragma unroll
        for (int mi = 0; mi < 4; mi++)
#pragma unroll
            for (int ni = 0; ni < 4; ni++)
                acc[mi][ni] = __builtin_amdgcn_mfma_f32_16x16x32_bf16(af[mi], bfv[ni], acc[mi][ni], 0, 0, 0);
    };

    stage(0, 0);
    stage(1, 1);
    int buf = 0;
    for (int kt = 0; kt < nk; kt++) {
        if (kt + 2 < nk) {
            int nbuf = buf + 2; if (nbuf >= 3) nbuf -= 3;
            stage(kt + 2, nbuf);
            WAIT_VM6();
        } else if (kt + 1 < nk) {
            WAIT_VM3();
        } else {
            WAIT_VM0();
        }
        BARRIER();
        compute(buf);
        WAIT_LGKM0();
        BARRIER();
        buf++; if (buf >= 3) buf = 0;
    }

    const int headBase = colBase >> 7;      // 0 or 2
    const int hl   = wn >> 7;               // head-local 0/1
    const int half = (wn >> 6) & 1;
    const float* aslp = a_src + (headBase + hl) * 128;
    const float* adlp = a_dst + (headBase + hl) * 128;
    float acoef[4], dcoef[4];
#pragma unroll
    for (int ni = 0; ni < 4; ni++) {
        int cl = half * 64 + ni * 16 + l16;
        acoef[ni] = aslp[cl];
        dcoef[ni] = adlp[cl];
    }

    float2* red = reinterpret_cast<float2*>(&Asl[0][0]);   // [128 rows][2 heads][2 halves]

#pragma unroll
    for (int mi = 0; mi < 4; mi++) {
#pragma unroll
        for (int rr = 0; rr < 4; rr++) {
            int lrow = wm + mi * 16 + q * 4 + rr;
            int grow = rowBase + lrow;
            bool ok = grow < M;
            float vs = 0.f, vd = 0.f;
#pragma unroll
            for (int ni = 0; ni < 4; ni++) {
                float hv = acc[mi][ni][rr];
                vs += hv * acoef[ni];
                vd += hv * dcoef[ni];
                if (ok) {
                    int gcol = colBase + wn + ni * 16 + l16;
                    Cc[(size_t)grow * N + gcol] = f2bf(hv);
                }
            }
#pragma unroll
            for (int d = 1; d < 16; d <<= 1) {
                vs += __shfl_xor(vs, d);
                vd += __shfl_xor(vd, d);
            }
            if (l16 == 0) red[lrow * 4 + hl * 2 + half] = make_float2(vs, vd);
        }
    }
    __syncthreads();
    if (tid < 256) {
        int row = tid >> 1, hh = tid & 1;
        int grow = rowBase + row;
        if (grow < M) {
            float2 a = red[row * 4 + hh * 2 + 0];
            float2 b = red[row * 4 + hh * 2 + 1];
            alS[(size_t)grow * HEADS + headBase + hh] = a.x + b.x;
            alD[(size_t)grow * HEADS + headBase + hh] = a.y + b.y;
        }
    }
}

// ---------------- bf16 MFMA GEMM layer 3 (BM=64, BN=128, BK=32), 3-stage -----------
__global__ __launch_bounds__(256) void gemm_l3(const unsigned short* __restrict__ A,
                                               const unsigned short* __restrict__ Bt,
                                               unsigned short* __restrict__ Cc,
                                               int M, int K,
                                               const float* __restrict__ a_src,
                                               const float* __restrict__ a_dst,
                                               float* __restrict__ alS,
                                               float* __restrict__ alD) {
    const int N = 128;
    __shared__ unsigned short Asl[3][64 * 32];    // 3 x 4 KB
    __shared__ unsigned short Bsl[3][128 * 32];   // 3 x 8 KB
    const int tid  = threadIdx.x;
    const int lane = tid & 63;
    const int wave = tid >> 6;
    const int rowBase = blockIdx.x * 64;
    const int wm = (wave & 1) * 32;               // 4 waves = 2 (m) x 2 (n)
    const int wn = (wave >> 1) * 64;
    const int q   = lane >> 4;
    const int l16 = lane & 15;

    const int ar  = tid >> 2;                     // A row 0..63
    const int acg = (tid & 3) ^ ((ar >> 1) & 3);
    int gaA = rowBase + ar; if (gaA >= M) gaA = M - 1;
    const unsigned short* gpA0 = A + (size_t)gaA * K + acg * 8;

    const int br0  = tid >> 2;                    // B rows 0..63
    const int bcg0 = (tid & 3) ^ ((br0 >> 1) & 3);
    const int br1  = (tid + 256) >> 2;            // B rows 64..127
    const int bcg1 = (tid & 3) ^ ((br1 >> 1) & 3);
    const unsigned short* gpB0 = Bt + (size_t)br0 * K + bcg0 * 8;
    const unsigned short* gpB1 = Bt + (size_t)br1 * K + bcg1 * 8;

    const int nk = K >> 5;                        // 16
    f32x4 acc[2][4] = {};

    auto stage = [&](int kt, int buf) {
        gld16(gpA0 + kt * 32, &Asl[buf][tid * 8]);
        gld16(gpB0 + kt * 32, &Bsl[buf][tid * 8]);
        gld16(gpB1 + kt * 32, &Bsl[buf][(size_t)(tid + 256) * 8]);
    };
    auto compute = [&](int buf) {
        bf16x8 af[2], bfv[4];
#pragma unroll
        for (int mi = 0; mi < 2; mi++) {
            int row = wm + mi * 16 + l16;
            int ch = q ^ ((row >> 1) & 3);
            af[mi] = *reinterpret_cast<const bf16x8*>(&Asl[buf][row * 32 + ch * 8]);
        }
#pragma unroll
        for (int ni = 0; ni < 4; ni++) {
            int row = wn + ni * 16 + l16;
            int ch = q ^ ((row >> 1) & 3);
            bfv[ni] = *reinterpret_cast<const bf16x8*>(&Bsl[buf][row * 32 + ch * 8]);
        }
#pragma unroll
        for (int mi = 0; mi < 2; mi++)
#pragma unroll
            for (int ni = 0; ni < 4; ni++)
                acc[mi][ni] = __builtin_amdgcn_mfma_f32_16x16x32_bf16(af[mi], bfv[ni], acc[mi][ni], 0, 0, 0);
    };

    stage(0, 0);
    stage(1, 1);
    int buf = 0;
    for (int kt = 0; kt < nk; kt++) {
        if (kt + 2 < nk) {
            int nbuf = buf + 2; if (nbuf >= 3) nbuf -= 3;
            stage(kt + 2, nbuf);
            WAIT_VM6();
        } else if (kt + 1 < nk) {
            WAIT_VM3();
        } else {
            WAIT_VM0();
        }
        BARRIER();
        compute(buf);
        WAIT_LGKM0();
        BARRIER();
        buf++; if (buf >= 3) buf = 0;
    }

    const int half = wn >> 6;
    float acoef[4], dcoef[4];
#pragma unroll
    for (int ni = 0; ni < 4; ni++) {
        int cl = wn + ni * 16 + l16;
        acoef[ni] = a_src[cl];
        dcoef[ni] = a_dst[cl];
    }

    float2* red = reinterpret_cast<float2*>(&Asl[0][0]);   // [64 rows][2 halves]

#pragma unroll
    for (int mi = 0; mi < 2; mi++) {
#pragma unroll
        for (int rr = 0; rr < 4; rr++) {
            int lrow = wm + mi * 16 + q * 4 + rr;
            int grow = rowBase + lrow;
            bool ok = grow < M;
            float vs = 0.f, vd = 0.f;
#pragma unroll
            for (int ni = 0; ni < 4; ni++) {
                float hv = acc[mi][ni][rr];
                vs += hv * acoef[ni];
                vd += hv * dcoef[ni];
                if (ok) {
                    int gcol = wn + ni * 16 + l16;
                    Cc[(size_t)grow * N + gcol] = f2bf(hv);
                }
            }
#pragma unroll
            for (int d = 1; d < 16; d <<= 1) {
                vs += __shfl_xor(vs, d);
                vd += __shfl_xor(vd, d);
            }
            if (l16 == 0) red[lrow * 2 + half] = make_float2(vs, vd);
        }
    }
    __syncthreads();
    if (tid < 64) {
        int grow = rowBase + tid;
        if (grow < M) {
            float2 a = red[tid * 2 + 0];
            float2 b = red[tid * 2 + 1];
            alS[grow] = a.x + b.x;
            alD[grow] = a.y + b.y;
        }
    }
}

// ------- fused segment softmax + aggregate, wave/node (R4 proven structure) --------
// LDS index/weight transport + 4-deep software-pipelined consume (benched <=41us).
// MODE 0: bf16 out + relu. MODE 2: fused risk head -> sigmoid -> out (fp32).
template <int H, int C, int MODE>
__global__ __launch_bounds__(256) void gat_aggregate(const unsigned short* __restrict__ hb,
                                                     const float* __restrict__ alS,
                                                     const float* __restrict__ alD,
                                                     const int* __restrict__ cursor,
                                                     const int* __restrict__ csr_src,
                                                     const float* __restrict__ bias,
                                                     unsigned short* __restrict__ outbuf,
                                                     int N,
                                                     const unsigned short* __restrict__ Ws1t,
                                                     const float* __restrict__ bs1,
                                                     const float* __restrict__ Ws2,
                                                     const float* __restrict__ bs2,
                                                     float* __restrict__ out) {
    constexpr int HC = H * C;
    constexpr int PER = HC / 64;
    __shared__ int   sIdx[4][16];
    __shared__ float sW[4][64];
    __shared__ float hrow[4][128];          // MODE 2 epilogue only

    int n = (blockIdx.x * blockDim.x + threadIdx.x) >> 6;
    int lane = threadIdx.x & 63;
    int wave = threadIdx.x >> 6;
    if (n >= N) return;
    int total = cursor[n]; if (total > MAXDEG) total = MAXDEG;
    const int* rowp = csr_src + (size_t)n * MAXDEG;

    const int grp  = lane >> 4;
    const int slot = lane & 15;
    const int myh  = (H == 4) ? grp : 0;
    const float adh = alD[n * H + myh];
    const unsigned short* hbl = hb + (size_t)lane * PER;
    const float* sWrow = &sW[wave][grp * 16];

    float m = -1e30f, dn = 0.f;
    float acc0 = 0.f, acc1 = 0.f, acc2 = 0.f, acc3 = 0.f,
          acc4 = 0.f, acc5 = 0.f, acc6 = 0.f, acc7 = 0.f;

    for (int base = 0; base < total; base += 16) {
        int cnt = total - base; if (cnt > 16) cnt = 16;
        bool act = slot < cnt;
        int s_l = rowp[act ? (base + slot) : base];
        float v = act ? lrelu(alS[s_l * H + myh] + adh) : -1e30f;

        float mc = v;
#pragma unroll
        for (int d = 1; d < 16; d <<= 1) mc = fmaxf(mc, __shfl_xor(mc, d));
        float pl = __expf(v - mc);
        float dc = pl;
#pragma unroll
        for (int d = 1; d < 16; d <<= 1) dc += __shfl_xor(dc, d);
        float nm = fmaxf(m, mc);
        float so = __expf(m - nm);
        float sc = __expf(mc - nm);
        dn = dn * so + dc * sc;
        m = nm;
        float wl = pl * sc;

        if (lane < 16) sIdx[wave][lane] = s_l;
        sW[wave][lane] = wl;

        acc0 *= so; acc1 *= so;
        if (PER == 8) {
            acc2 *= so; acc3 *= so; acc4 *= so; acc5 *= so;
            acc6 *= so; acc7 *= so;
        }

        int cntR = (cnt + 3) & ~3;

        if (PER == 8) {
            int4   sI = *reinterpret_cast<const int4*>(&sIdx[wave][0]);
            float4 wv = *reinterpret_cast<const float4*>(&sWrow[0]);
            uint4 gA0 = *reinterpret_cast<const uint4*>(hbl + (size_t)sI.x * HC);
            uint4 gA1 = *reinterpret_cast<const uint4*>(hbl + (size_t)sI.y * HC);
            uint4 gA2 = *reinterpret_cast<const uint4*>(hbl + (size_t)sI.z * HC);
            uint4 gA3 = *reinterpret_cast<const uint4*>(hbl + (size_t)sI.w * HC);
            for (int i = 0; i < cntR; i += 4) {
                int4 sI2 = {}; float4 wv2 = {};
                uint4 gB0 = {}, gB1 = {}, gB2 = {}, gB3 = {};
                if (i + 4 < cntR) {
                    sI2 = *reinterpret_cast<const int4*>(&sIdx[wave][i + 4]);
                    wv2 = *reinterpret_cast<const float4*>(&sWrow[i + 4]);
                    gB0 = *reinterpret_cast<const uint4*>(hbl + (size_t)sI2.x * HC);
                    gB1 = *reinterpret_cast<const uint4*>(hbl + (size_t)sI2.y * HC);
                    gB2 = *reinterpret_cast<const uint4*>(hbl + (size_t)sI2.z * HC);
                    gB3 = *reinterpret_cast<const uint4*>(hbl + (size_t)sI2.w * HC);
                }
#define CONSUME(G, W)                                                   \
                { uint4 rc = G; float w = W;                            \
                  acc0 += bf_lo(rc.x) * w; acc1 += bf_hi(rc.x) * w;     \
                  acc2 += bf_lo(rc.y) * w; acc3 += bf_hi(rc.y) * w;     \
                  acc4 += bf_lo(rc.z) * w; acc5 += bf_hi(rc.z) * w;     \
                  acc6 += bf_lo(rc.w) * w; acc7 += bf_hi(rc.w) * w; }
                CONSUME(gA0, wv.x); CONSUME(gA1, wv.y);
                CONSUME(gA2, wv.z); CONSUME(gA3, wv.w);
#undef CONSUME
                sI = sI2; wv = wv2;
                gA0 = gB0; gA1 = gB1; gA2 = gB2; gA3 = gB3;
            }
        } else {
            int4   sI = *reinterpret_cast<const int4*>(&sIdx[wave][0]);
            float4 wv = *reinterpret_cast<const float4*>(&sWrow[0]);
            unsigned gA0 = *reinterpret_cast<const unsigned*>(hbl + (size_t)sI.x * HC);
            unsigned gA1 = *reinterpret_cast<const unsigned*>(hbl + (size_t)sI.y * HC);
            unsigned gA2 = *reinterpret_cast<const unsigned*>(hbl + (size_t)sI.z * HC);
            unsigned gA3 = *reinterpret_cast<const unsigned*>(hbl + (size_t)sI.w * HC);
            for (int i = 0; i < cntR; i += 4) {
                int4 sI2 = {}; float4 wv2 = {};
                unsigned gB0 = 0, gB1 = 0, gB2 = 0, gB3 = 0;
                if (i + 4 < cntR) {
                    sI2 = *reinterpret_cast<const int4*>(&sIdx[wave][i + 4]);
                    wv2 = *reinterpret_cast<const float4*>(&sWrow[i + 4]);
                    gB0 = *reinterpret_cast<const unsigned*>(hbl + (size_t)sI2.x * HC);
                    gB1 = *reinterpret_cast<const unsigned*>(hbl + (size_t)sI2.y * HC);
                    gB2 = *reinterpret_cast<const unsigned*>(hbl + (size_t)sI2.z * HC);
                    gB3 = *reinterpret_cast<const unsigned*>(hbl + (size_t)sI2.w * HC);
                }
                acc0 += bf_lo(gA0) * wv.x; acc1 += bf_hi(gA0) * wv.x;
                acc0 += bf_lo(gA1) * wv.y; acc1 += bf_hi(gA1) * wv.y;
                acc0 += bf_lo(gA2) * wv.z; acc1 += bf_hi(gA2) * wv.z;
                acc0 += bf_lo(gA3) * wv.w; acc1 += bf_hi(gA3) * wv.w;
                sI = sI2; wv = wv2;
                gA0 = gB0; gA1 = gB1; gA2 = gB2; gA3 = gB3;
            }
        }
    }

    float invd = 1.f / dn;
    const float* bp = bias + lane * PER;
    if (MODE == 0) {
        unsigned short* op = outbuf + (size_t)n * HC + lane * PER;
        float o0 = acc0 * invd + bp[0], o1 = acc1 * invd + bp[1];
        float o2 = acc2 * invd + bp[2], o3 = acc3 * invd + bp[3];
        float o4 = acc4 * invd + bp[4], o5 = acc5 * invd + bp[5];
        float o6 = acc6 * invd + bp[6], o7 = acc7 * invd + bp[7];
        o0 = fmaxf(o0, 0.f); o1 = fmaxf(o1, 0.f); o2 = fmaxf(o2, 0.f); o3 = fmaxf(o3, 0.f);
        o4 = fmaxf(o4, 0.f); o5 = fmaxf(o5, 0.f); o6 = fmaxf(o6, 0.f); o7 = fmaxf(o7, 0.f);
        op[0] = f2bf(o0); op[1] = f2bf(o1); op[2] = f2bf(o2); op[3] = f2bf(o3);
        op[4] = f2bf(o4); op[5] = f2bf(o5); op[6] = f2bf(o6); op[7] = f2bf(o7);
    } else {
        // ---- fused risk head: sigmoid(relu(h3@Ws1+bs1)@Ws2+bs2) ----
        float o0 = acc0 * invd + bp[0], o1 = acc1 * invd + bp[1];
        reinterpret_cast<float2*>(&hrow[wave][0])[lane] = make_float2(o0, o1);
        WAIT_LGKM0();                      // same-wave LDS visibility
        const float* hr = &hrow[wave][0];
        const unsigned short* wrow = Ws1t + (size_t)lane * 128;
        float s = bs1[lane];
#pragma unroll
        for (int k = 0; k < 128; k += 8) {
            uint4 wv = *reinterpret_cast<const uint4*>(&wrow[k]);
            s += hr[k + 0] * bf_lo(wv.x) + hr[k + 1] * bf_hi(wv.x)
               + hr[k + 2] * bf_lo(wv.y) + hr[k + 3] * bf_hi(wv.y)
               + hr[k + 4] * bf_lo(wv.z) + hr[k + 5] * bf_hi(wv.z)
               + hr[k + 6] * bf_lo(wv.w) + hr[k + 7] * bf_hi(wv.w);
        }
        float p = fmaxf(s, 0.f) * Ws2[lane];
#pragma unroll
        for (int d = 1; d < 64; d <<= 1) p += __shfl_xor(p, d);
        if (lane == 0) out[n] = 1.f / (1.f + __expf(-(p + bs2[0])));
    }
}

// ---------------- launch ----------------
extern "C" void kernel_launch(void* const* d_in, const int* in_sizes, int n_in,
                              void* d_out, int out_size, void* d_ws, size_t ws_size,
                              hipStream_t stream) {
    const float* x   = (const float*)d_in[0];
    const int*   ei  = (const int*)d_in[1];
    const float* W1  = (const float*)d_in[2];
    const float* as1 = (const float*)d_in[3];
    const float* ad1 = (const float*)d_in[4];
    const float* b1  = (const float*)d_in[5];
    const float* W2  = (const float*)d_in[6];
    const float* as2 = (const float*)d_in[7];
    const float* ad2 = (const float*)d_in[8];
    const float* b2  = (const float*)d_in[9];
    const float* W3  = (const float*)d_in[10];
    const float* as3 = (const float*)d_in[11];
    const float* ad3 = (const float*)d_in[12];
    const float* b3  = (const float*)d_in[13];
    const float* Ws1 = (const float*)d_in[14];
    const float* bs1 = (const float*)d_in[15];
    const float* Ws2 = (const float*)d_in[16];
    const float* bs2 = (const float*)d_in[17];

    const int N = out_size;            // 20000
    const int E = in_sizes[1] / 2;     // 160000
    const int D = in_sizes[0] / N;     // 768
    const int HC = 512, H = 4, C = 128;
    const int Etot = E + N;

    char* p = (char*)d_ws;
    auto alloc = [&](size_t bytes) -> void* {
        void* q = (void*)p;
        p += (bytes + 255) & ~(size_t)255;
        return q;
    };
    // --- zeroed region (cursor only) ---
    char*  zbeg   = p;
    int*   cursor = (int*)alloc((size_t)N * 4);
    char*  zend   = p;
    // --- rest ---
    float* alS1   = (float*)alloc((size_t)N * H * 4);
    float* alD1   = (float*)alloc((size_t)N * H * 4);
    float* alS2   = (float*)alloc((size_t)N * H * 4);
    float* alD2   = (float*)alloc((size_t)N * H * 4);
    float* alS3   = (float*)alloc((size_t)N * 4);
    float* alD3   = (float*)alloc((size_t)N * 4);
    int*   csr    = (int*)alloc((size_t)N * MAXDEG * 4);
    unsigned short* hbuf = (unsigned short*)alloc((size_t)N * HC * 2);
    unsigned short* obf  = (unsigned short*)alloc((size_t)N * HC * 2);
    unsigned short* xbf  = (unsigned short*)alloc((size_t)N * D * 2);
    unsigned short* W1t  = (unsigned short*)alloc((size_t)D * HC * 2);
    unsigned short* W2t  = (unsigned short*)alloc((size_t)HC * HC * 2);
    unsigned short* W3t  = (unsigned short*)alloc((size_t)HC * C * 2);
    unsigned short* Ws1t = (unsigned short*)alloc((size_t)C * 64 * 2);

    hipMemsetAsync(zbeg, 0, (size_t)(zend - zbeg), stream);

    // ---- fused preprocessing (x-cast + transposes + padded-CSR scatter) ----
    {
        int n4 = N * D / 4;
        int c0 = (n4 + 255) / 256;
        int c1 = (D * HC + 255) / 256;
        int c2 = (HC * HC + 255) / 256;
        int c3 = (HC * C + 255) / 256;
        int c4 = (128 * 64 + 255) / 256;
        int c5 = (Etot + 255) / 256;
        int total = c0 + c1 + c2 + c3 + c4 + c5;
        preproc_kernel<<<total, 256, 0, stream>>>(
            x, xbf, n4, W1, W1t, W2, W2t, W3, W3t, Ws1, Ws1t,
            ei, E, N, cursor, csr, c0, c1, c2, c3, c4, D, HC, C);
    }

    int node_blocks = (N + 3) / 4;          // one wave per node
    int rowTiles128 = (N + 127) / 128;      // 157
    int rowTiles64  = (N + 63) / 64;        // 313

    // ---- layer 1 ----
    gemm_big<4><<<rowTiles128 * 2, 512, 0, stream>>>(
        xbf, W1t, hbuf, N, HC, D, rowTiles128, as1, ad1, alS1, alD1);
    gat_aggregate<4, 128, 0><<<node_blocks, 256, 0, stream>>>(
        hbuf, alS1, alD1, cursor, csr, b1, obf, N,
        nullptr, nullptr, nullptr, nullptr, nullptr);

    // ---- layer 2 ----
    gemm_big<4><<<rowTiles128 * 2, 512, 0, stream>>>(
        obf, W2t, hbuf, N, HC, HC, rowTiles128, as2, ad2, alS2, alD2);
    gat_aggregate<4, 128, 0><<<node_blocks, 256, 0, stream>>>(
        hbuf, alS2, alD2, cursor, csr, b2, obf, N,
        nullptr, nullptr, nullptr, nullptr, nullptr);

    // ---- layer 3 (H=1) + fused risk head ----
    gemm_l3<<<rowTiles64, 256, 0, stream>>>(
        obf, W3t, hbuf, N, HC, as3, ad3, alS3, alD3);
    gat_aggregate<1, 128, 2><<<node_blocks, 256, 0, stream>>>(
        hbuf, alS3, alD3, cursor, csr, b3, nullptr, N,
        Ws1t, bs1, Ws2, bs2, (float*)d_out);
}

// Round 9
// 287.577 us; speedup vs baseline: 1.1002x; 1.1002x over previous
//
#include <hip/hip_runtime.h>
#include <hip/hip_bf16.h>
#include <math.h>

#define NEG_SLOPE 0.2f
#define MAXDEG 64

typedef __attribute__((ext_vector_type(8))) __bf16 bf16x8;
typedef __attribute__((ext_vector_type(4))) float f32x4;

// ---------------- helpers ----------------
__device__ inline float lrelu(float v) { return v > 0.f ? v : NEG_SLOPE * v; }

__device__ inline unsigned short f2bf(float f) {
    __hip_bfloat16 h = __float2bfloat16(f);
    return *reinterpret_cast<unsigned short*>(&h);
}
__device__ inline float bf_lo(unsigned u) { return __uint_as_float(u << 16); }
__device__ inline float bf_hi(unsigned u) { return __uint_as_float(u & 0xffff0000u); }

__device__ inline void gld16(const unsigned short* gp, unsigned short* lp) {
    __builtin_amdgcn_global_load_lds(
        (const __attribute__((address_space(1))) void*)gp,
        (__attribute__((address_space(3))) void*)lp, 16, 0, 0);
}

__device__ inline void transpose_one(const float* __restrict__ in,
                                     unsigned short* __restrict__ out,
                                     int K, int N, int idx) {
    if (idx >= K * N) return;
    int n = idx / K, k = idx % K;
    out[(size_t)n * K + k] = f2bf(in[(size_t)k * N + n]);
}

// ---- raw sync primitives (no vmcnt(0) drain like __syncthreads) ----
#define BARRIER()    asm volatile("s_barrier" ::: "memory")
#define WAIT_LGKM0() asm volatile("s_waitcnt lgkmcnt(0)" ::: "memory")
#define WAIT_VM0()   asm volatile("s_waitcnt vmcnt(0)" ::: "memory")
#define WAIT_VM3()   asm volatile("s_waitcnt vmcnt(3)" ::: "memory")
#define WAIT_VM6()   asm volatile("s_waitcnt vmcnt(6)" ::: "memory")

// -------- fused preprocessing: x-cast + 4 transposes + padded-CSR scatter ----------
// Direct scatter (atomic cursor) replaces deg-count + scan + scatter: 1 kernel not 3.
__global__ __launch_bounds__(256) void preproc_kernel(
    const float* __restrict__ x, unsigned short* __restrict__ xbf, int n4,
    const float* __restrict__ W1, unsigned short* __restrict__ W1t,
    const float* __restrict__ W2, unsigned short* __restrict__ W2t,
    const float* __restrict__ W3, unsigned short* __restrict__ W3t,
    const float* __restrict__ Ws1, unsigned short* __restrict__ Ws1t,
    const int* __restrict__ ei, int E, int N,
    int* __restrict__ cursor, int* __restrict__ csr,
    int c0, int c1, int c2, int c3, int c4,
    int D, int HC, int C) {
    int b = blockIdx.x;
    int t = threadIdx.x;
    if (b < c0) {                                   // x fp32 -> bf16 (float4)
        int i = b * 256 + t;
        if (i < n4) {
            float4 v = reinterpret_cast<const float4*>(x)[i];
            ushort4 o;
            o.x = f2bf(v.x); o.y = f2bf(v.y); o.z = f2bf(v.z); o.w = f2bf(v.w);
            reinterpret_cast<ushort4*>(xbf)[i] = o;
        }
        return;
    }
    b -= c0;
    if (b < c1) { transpose_one(W1, W1t, D, HC, b * 256 + t); return; }
    b -= c1;
    if (b < c2) { transpose_one(W2, W2t, HC, HC, b * 256 + t); return; }
    b -= c2;
    if (b < c3) { transpose_one(W3, W3t, HC, C, b * 256 + t); return; }
    b -= c3;
    if (b < c4) { transpose_one(Ws1, Ws1t, 128, 64, b * 256 + t); return; }
    b -= c4;
    {                                               // direct padded-CSR scatter
        int e = b * 256 + t;
        if (e < E + N) {
            int src, dst;
            if (e < E) { src = ei[e]; dst = ei[E + e]; }
            else       { src = dst = e - E; }
            int pos = atomicAdd(&cursor[dst], 1);
            if (pos < MAXDEG) csr[dst * MAXDEG + pos] = src;
        }
    }
}

// ---------------- bf16 MFMA GEMM (BM=128, BN=256, BK=32), 8 waves, 3-stage ---------
// Depth-2 prefetch: stage(kt+2) in flight while computing kt; wait vmcnt(6)/3/0.
// LDS XOR swizzle on (row>>1)&3 -> 2-way LDS reads (free).
template <int HEADS>
__global__ __launch_bounds__(512) void gemm_big(const unsigned short* __restrict__ A,
                                                const unsigned short* __restrict__ Bt,
                                                unsigned short* __restrict__ Cc,
                                                int M, int N, int K, int rowTiles,
                                                const float* __restrict__ a_src,
                                                const float* __restrict__ a_dst,
                                                float* __restrict__ alS,
                                                float* __restrict__ alD) {
    __shared__ unsigned short Asl[3][128 * 32];   // 3 x 8 KB
    __shared__ unsigned short Bsl[3][256 * 32];   // 3 x 16 KB
    const int tid  = threadIdx.x;
    const int lane = tid & 63;
    const int wave = tid >> 6;

    // XCD-aware decode: 2 col-tiles of one row-tile share an XCD
    int r, c;
    {
        int b = blockIdx.x;
        int mainRows = rowTiles & ~7;
        int mainBlocks = mainRows * 2;
        if (b < mainBlocks) {
            int xcd = b & 7;
            c = (b >> 3) & 1;
            r = (b >> 4) * 8 + xcd;
        } else {
            int idx = b - mainBlocks;
            r = mainRows + (idx >> 1);
            c = idx & 1;
        }
    }
    const int rowBase = r * 128;
    const int colBase = c * 256;
    const int wm = (wave & 1) * 64;        // 8 waves = 2 (m) x 4 (n)
    const int wn = (wave >> 1) * 64;
    const int q   = lane >> 4;
    const int l16 = lane & 15;

    const int ar  = tid >> 2;                       // A row 0..127
    const int acg = (tid & 3) ^ ((ar >> 1) & 3);
    int gaA = rowBase + ar; if (gaA >= M) gaA = M - 1;
    const unsigned short* gpA0 = A + (size_t)gaA * K + acg * 8;

    const int br0  = tid >> 2;                      // B rows 0..127
    const int bcg0 = (tid & 3) ^ ((br0 >> 1) & 3);
    const int br1  = (tid + 512) >> 2;              // B rows 128..255
    const int bcg1 = (tid & 3) ^ ((br1 >> 1) & 3);
    const unsigned short* gpB0 = Bt + (size_t)(colBase + br0) * K + bcg0 * 8;
    const unsigned short* gpB1 = Bt + (size_t)(colBase + br1) * K + bcg1 * 8;

    const int nk = K >> 5;                          // 24 (K=768) or 16 (K=512)
    f32x4 acc[4][4] = {};

    auto stage = [&](int kt, int buf) {
        gld16(gpA0 + kt * 32, &Asl[buf][tid * 8]);
        gld16(gpB0 + kt * 32, &Bsl[buf][tid * 8]);
        gld16(gpB1 + kt * 32, &Bsl[buf][(size_t)(tid + 512) * 8]);
    };
    auto compute = [&](int buf) {
        bf16x8 af[4], bfv[4];
#pragma unroll
        for (int mi = 0; mi < 4; mi++) {
            int row = wm + mi * 16 + l16;
            int ch = q ^ ((row >> 1) & 3);
            af[mi] = *reinterpret_cast<const bf16x8*>(&Asl[buf][row * 32 + ch * 8]);
        }
#pragma unroll
        for (int ni = 0; ni < 4; ni++) {
            int row = wn + ni * 16 + l16;
            int ch = q ^ ((row >> 1) & 3);
            bfv[ni] = *reinterpret_cast<const bf16x8*>(&Bsl[buf][row * 32 + ch * 8]);
        }
#pragma unroll
        for (int mi = 0; mi < 4; mi++)
#pragma unroll
            for (int ni = 0; ni < 4; ni++)
                acc[mi][ni] = __builtin_amdgcn_mfma_f32_16x16x32_bf16(af[mi], bfv[ni], acc[mi][ni], 0, 0, 0);
    };

    stage(0, 0);
    stage(1, 1);
    int buf = 0;
    for (int kt = 0; kt < nk; kt++) {
        if (kt + 2 < nk) {
            int nbuf = buf + 2; if (nbuf >= 3) nbuf -= 3;
            stage(kt + 2, nbuf);
            WAIT_VM6();
        } else if (kt + 1 < nk) {
            WAIT_VM3();
        } else {
            WAIT_VM0();
        }
        BARRIER();                          // buf's data visible to all
        compute(buf);
        WAIT_LGKM0();
        BARRIER();                          // all waves done reading buf
        buf++; if (buf >= 3) buf = 0;
    }

    // epilogue: this wave's 64 cols = half of one head (C=128)
    const int headBase = colBase >> 7;      // 0 or 2
    const int hl   = wn >> 7;               // head-local 0/1
    const int half = (wn >> 6) & 1;
    const float* aslp = a_src + (headBase + hl) * 128;
    const float* adlp = a_dst + (headBase + hl) * 128;
    float acoef[4], dcoef[4];
#pragma unroll
    for (int ni = 0; ni < 4; ni++) {
        int cl = half * 64 + ni * 16 + l16;
        acoef[ni] = aslp[cl];
        dcoef[ni] = adlp[cl];
    }

    float2* red = reinterpret_cast<float2*>(&Asl[0][0]);   // [128 rows][2 heads][2 halves]

#pragma unroll
    for (int mi = 0; mi < 4; mi++) {
#pragma unroll
        for (int rr = 0; rr < 4; rr++) {
            int lrow = wm + mi * 16 + q * 4 + rr;
            int grow = rowBase + lrow;
            bool ok = grow < M;
            float vs = 0.f, vd = 0.f;
#pragma unroll
            for (int ni = 0; ni < 4; ni++) {
                float hv = acc[mi][ni][rr];
                vs += hv * acoef[ni];
                vd += hv * dcoef[ni];
                if (ok) {
                    int gcol = colBase + wn + ni * 16 + l16;
                    Cc[(size_t)grow * N + gcol] = f2bf(hv);
                }
            }
#pragma unroll
            for (int d = 1; d < 16; d <<= 1) {
                vs += __shfl_xor(vs, d);
                vd += __shfl_xor(vd, d);
            }
            if (l16 == 0) red[lrow * 4 + hl * 2 + half] = make_float2(vs, vd);
        }
    }
    __syncthreads();
    if (tid < 256) {
        int row = tid >> 1, hh = tid & 1;
        int grow = rowBase + row;
        if (grow < M) {
            float2 a = red[row * 4 + hh * 2 + 0];
            float2 b = red[row * 4 + hh * 2 + 1];
            alS[(size_t)grow * HEADS + headBase + hh] = a.x + b.x;
            alD[(size_t)grow * HEADS + headBase + hh] = a.y + b.y;
        }
    }
}

// ---------------- bf16 MFMA GEMM layer 3 (BM=64, BN=128, BK=32), 3-stage -----------
__global__ __launch_bounds__(256) void gemm_l3(const unsigned short* __restrict__ A,
                                               const unsigned short* __restrict__ Bt,
                                               unsigned short* __restrict__ Cc,
                                               int M, int K,
                                               const float* __restrict__ a_src,
                                               const float* __restrict__ a_dst,
                                               float* __restrict__ alS,
                                               float* __restrict__ alD) {
    const int N = 128;
    __shared__ unsigned short Asl[3][64 * 32];    // 3 x 4 KB
    __shared__ unsigned short Bsl[3][128 * 32];   // 3 x 8 KB
    const int tid  = threadIdx.x;
    const int lane = tid & 63;
    const int wave = tid >> 6;
    const int rowBase = blockIdx.x * 64;
    const int wm = (wave & 1) * 32;               // 4 waves = 2 (m) x 2 (n)
    const int wn = (wave >> 1) * 64;
    const int q   = lane >> 4;
    const int l16 = lane & 15;

    const int ar  = tid >> 2;                     // A row 0..63
    const int acg = (tid & 3) ^ ((ar >> 1) & 3);
    int gaA = rowBase + ar; if (gaA >= M) gaA = M - 1;
    const unsigned short* gpA0 = A + (size_t)gaA * K + acg * 8;

    const int br0  = tid >> 2;                    // B rows 0..63
    const int bcg0 = (tid & 3) ^ ((br0 >> 1) & 3);
    const int br1  = (tid + 256) >> 2;            // B rows 64..127
    const int bcg1 = (tid & 3) ^ ((br1 >> 1) & 3);
    const unsigned short* gpB0 = Bt + (size_t)br0 * K + bcg0 * 8;
    const unsigned short* gpB1 = Bt + (size_t)br1 * K + bcg1 * 8;

    const int nk = K >> 5;                        // 16
    f32x4 acc[2][4] = {};

    auto stage = [&](int kt, int buf) {
        gld16(gpA0 + kt * 32, &Asl[buf][tid * 8]);
        gld16(gpB0 + kt * 32, &Bsl[buf][tid * 8]);
        gld16(gpB1 + kt * 32, &Bsl[buf][(size_t)(tid + 256) * 8]);
    };
    auto compute = [&](int buf) {
        bf16x8 af[2], bfv[4];
#pragma unroll
        for (int mi = 0; mi < 2; mi++) {
            int row = wm + mi * 16 + l16;
            int ch = q ^ ((row >> 1) & 3);
            af[mi] = *reinterpret_cast<const bf16x8*>(&Asl[buf][row * 32 + ch * 8]);
        }
#pragma unroll
        for (int ni = 0; ni < 4; ni++) {
            int row = wn + ni * 16 + l16;
            int ch = q ^ ((row >> 1) & 3);
            bfv[ni] = *reinterpret_cast<const bf16x8*>(&Bsl[buf][row * 32 + ch * 8]);
        }
#pragma unroll
        for (int mi = 0; mi < 2; mi++)
#pragma unroll
            for (int ni = 0; ni < 4; ni++)
                acc[mi][ni] = __builtin_amdgcn_mfma_f32_16x16x32_bf16(af[mi], bfv[ni], acc[mi][ni], 0, 0, 0);
    };

    stage(0, 0);
    stage(1, 1);
    int buf = 0;
    for (int kt = 0; kt < nk; kt++) {
        if (kt + 2 < nk) {
            int nbuf = buf + 2; if (nbuf >= 3) nbuf -= 3;
            stage(kt + 2, nbuf);
            WAIT_VM6();
        } else if (kt + 1 < nk) {
            WAIT_VM3();
        } else {
            WAIT_VM0();
        }
        BARRIER();
        compute(buf);
        WAIT_LGKM0();
        BARRIER();
        buf++; if (buf >= 3) buf = 0;
    }

    const int half = wn >> 6;
    float acoef[4], dcoef[4];
#pragma unroll
    for (int ni = 0; ni < 4; ni++) {
        int cl = wn + ni * 16 + l16;
        acoef[ni] = a_src[cl];
        dcoef[ni] = a_dst[cl];
    }

    float2* red = reinterpret_cast<float2*>(&Asl[0][0]);   // [64 rows][2 halves]

#pragma unroll
    for (int mi = 0; mi < 2; mi++) {
#pragma unroll
        for (int rr = 0; rr < 4; rr++) {
            int lrow = wm + mi * 16 + q * 4 + rr;
            int grow = rowBase + lrow;
            bool ok = grow < M;
            float vs = 0.f, vd = 0.f;
#pragma unroll
            for (int ni = 0; ni < 4; ni++) {
                float hv = acc[mi][ni][rr];
                vs += hv * acoef[ni];
                vd += hv * dcoef[ni];
                if (ok) {
                    int gcol = wn + ni * 16 + l16;
                    Cc[(size_t)grow * N + gcol] = f2bf(hv);
                }
            }
#pragma unroll
            for (int d = 1; d < 16; d <<= 1) {
                vs += __shfl_xor(vs, d);
                vd += __shfl_xor(vd, d);
            }
            if (l16 == 0) red[lrow * 2 + half] = make_float2(vs, vd);
        }
    }
    __syncthreads();
    if (tid < 64) {
        int grow = rowBase + tid;
        if (grow < M) {
            float2 a = red[tid * 2 + 0];
            float2 b = red[tid * 2 + 1];
            alS[grow] = a.x + b.x;
            alD[grow] = a.y + b.y;
        }
    }
}

// ---------------- fused segment softmax + aggregate, wave/node (padded CSR) --------
template <int H, int C, int MODE>
__global__ __launch_bounds__(256) void gat_aggregate(const unsigned short* __restrict__ hb,
                                                     const float* __restrict__ alS,
                                                     const float* __restrict__ alD,
                                                     const int* __restrict__ cursor,
                                                     const int* __restrict__ csr_src,
                                                     const float* __restrict__ bias,
                                                     unsigned short* __restrict__ outbuf,
                                                     int N) {
    constexpr int HC = H * C;
    constexpr int PER = HC / 64;
    __shared__ int   sIdx[4][16];
    __shared__ float sW[4][64];

    int n = (blockIdx.x * blockDim.x + threadIdx.x) >> 6;
    int lane = threadIdx.x & 63;
    int wave = threadIdx.x >> 6;
    if (n >= N) return;
    int total = cursor[n]; if (total > MAXDEG) total = MAXDEG;
    const int* rowp = csr_src + (size_t)n * MAXDEG;

    const int grp  = lane >> 4;
    const int slot = lane & 15;
    const int myh  = (H == 4) ? grp : 0;
    const float adh = alD[n * H + myh];
    const unsigned short* hbl = hb + (size_t)lane * PER;
    const float* sWrow = &sW[wave][grp * 16];

    float m = -1e30f, dn = 0.f;
    float acc0 = 0.f, acc1 = 0.f, acc2 = 0.f, acc3 = 0.f,
          acc4 = 0.f, acc5 = 0.f, acc6 = 0.f, acc7 = 0.f;

    for (int base = 0; base < total; base += 16) {
        int cnt = total - base; if (cnt > 16) cnt = 16;
        bool act = slot < cnt;
        int s_l = rowp[act ? (base + slot) : base];
        float v = act ? lrelu(alS[s_l * H + myh] + adh) : -1e30f;

        float mc = v;
#pragma unroll
        for (int d = 1; d < 16; d <<= 1) mc = fmaxf(mc, __shfl_xor(mc, d));
        float pl = __expf(v - mc);
        float dc = pl;
#pragma unroll
        for (int d = 1; d < 16; d <<= 1) dc += __shfl_xor(dc, d);
        float nm = fmaxf(m, mc);
        float so = __expf(m - nm);
        float sc = __expf(mc - nm);
        dn = dn * so + dc * sc;
        m = nm;
        float wl = pl * sc;

        if (lane < 16) sIdx[wave][lane] = s_l;
        sW[wave][lane] = wl;

        acc0 *= so; acc1 *= so;
        if (PER == 8) {
            acc2 *= so; acc3 *= so; acc4 *= so; acc5 *= so;
            acc6 *= so; acc7 *= so;
        }

        int cntR = (cnt + 3) & ~3;

        if (PER == 8) {
            int4   sI = *reinterpret_cast<const int4*>(&sIdx[wave][0]);
            float4 wv = *reinterpret_cast<const float4*>(&sWrow[0]);
            uint4 gA0 = *reinterpret_cast<const uint4*>(hbl + (size_t)sI.x * HC);
            uint4 gA1 = *reinterpret_cast<const uint4*>(hbl + (size_t)sI.y * HC);
            uint4 gA2 = *reinterpret_cast<const uint4*>(hbl + (size_t)sI.z * HC);
            uint4 gA3 = *reinterpret_cast<const uint4*>(hbl + (size_t)sI.w * HC);
            for (int i = 0; i < cntR; i += 4) {
                int4 sI2 = {}; float4 wv2 = {};
                uint4 gB0 = {}, gB1 = {}, gB2 = {}, gB3 = {};
                if (i + 4 < cntR) {
                    sI2 = *reinterpret_cast<const int4*>(&sIdx[wave][i + 4]);
                    wv2 = *reinterpret_cast<const float4*>(&sWrow[i + 4]);
                    gB0 = *reinterpret_cast<const uint4*>(hbl + (size_t)sI2.x * HC);
                    gB1 = *reinterpret_cast<const uint4*>(hbl + (size_t)sI2.y * HC);
                    gB2 = *reinterpret_cast<const uint4*>(hbl + (size_t)sI2.z * HC);
                    gB3 = *reinterpret_cast<const uint4*>(hbl + (size_t)sI2.w * HC);
                }
#define CONSUME(G, W)                                                   \
                { uint4 rc = G; float w = W;                            \
                  acc0 += bf_lo(rc.x) * w; acc1 += bf_hi(rc.x) * w;     \
                  acc2 += bf_lo(rc.y) * w; acc3 += bf_hi(rc.y) * w;     \
                  acc4 += bf_lo(rc.z) * w; acc5 += bf_hi(rc.z) * w;     \
                  acc6 += bf_lo(rc.w) * w; acc7 += bf_hi(rc.w) * w; }
                CONSUME(gA0, wv.x); CONSUME(gA1, wv.y);
                CONSUME(gA2, wv.z); CONSUME(gA3, wv.w);
#undef CONSUME
                sI = sI2; wv = wv2;
                gA0 = gB0; gA1 = gB1; gA2 = gB2; gA3 = gB3;
            }
        } else {
            int4   sI = *reinterpret_cast<const int4*>(&sIdx[wave][0]);
            float4 wv = *reinterpret_cast<const float4*>(&sWrow[0]);
            unsigned gA0 = *reinterpret_cast<const unsigned*>(hbl + (size_t)sI.x * HC);
            unsigned gA1 = *reinterpret_cast<const unsigned*>(hbl + (size_t)sI.y * HC);
            unsigned gA2 = *reinterpret_cast<const unsigned*>(hbl + (size_t)sI.z * HC);
            unsigned gA3 = *reinterpret_cast<const unsigned*>(hbl + (size_t)sI.w * HC);
            for (int i = 0; i < cntR; i += 4) {
                int4 sI2 = {}; float4 wv2 = {};
                unsigned gB0 = 0, gB1 = 0, gB2 = 0, gB3 = 0;
                if (i + 4 < cntR) {
                    sI2 = *reinterpret_cast<const int4*>(&sIdx[wave][i + 4]);
                    wv2 = *reinterpret_cast<const float4*>(&sWrow[i + 4]);
                    gB0 = *reinterpret_cast<const unsigned*>(hbl + (size_t)sI2.x * HC);
                    gB1 = *reinterpret_cast<const unsigned*>(hbl + (size_t)sI2.y * HC);
                    gB2 = *reinterpret_cast<const unsigned*>(hbl + (size_t)sI2.z * HC);
                    gB3 = *reinterpret_cast<const unsigned*>(hbl + (size_t)sI2.w * HC);
                }
                acc0 += bf_lo(gA0) * wv.x; acc1 += bf_hi(gA0) * wv.x;
                acc0 += bf_lo(gA1) * wv.y; acc1 += bf_hi(gA1) * wv.y;
                acc0 += bf_lo(gA2) * wv.z; acc1 += bf_hi(gA2) * wv.z;
                acc0 += bf_lo(gA3) * wv.w; acc1 += bf_hi(gA3) * wv.w;
                sI = sI2; wv = wv2;
                gA0 = gB0; gA1 = gB1; gA2 = gB2; gA3 = gB3;
            }
        }
    }

    float invd = 1.f / dn;
    unsigned short* op = outbuf + (size_t)n * HC + lane * PER;
    const float* bp = bias + lane * PER;
    if (PER == 8) {
        float o0 = acc0 * invd + bp[0], o1 = acc1 * invd + bp[1];
        float o2 = acc2 * invd + bp[2], o3 = acc3 * invd + bp[3];
        float o4 = acc4 * invd + bp[4], o5 = acc5 * invd + bp[5];
        float o6 = acc6 * invd + bp[6], o7 = acc7 * invd + bp[7];
        if (MODE == 0) {
            o0 = fmaxf(o0, 0.f); o1 = fmaxf(o1, 0.f); o2 = fmaxf(o2, 0.f); o3 = fmaxf(o3, 0.f);
            o4 = fmaxf(o4, 0.f); o5 = fmaxf(o5, 0.f); o6 = fmaxf(o6, 0.f); o7 = fmaxf(o7, 0.f);
        }
        op[0] = f2bf(o0); op[1] = f2bf(o1); op[2] = f2bf(o2); op[3] = f2bf(o3);
        op[4] = f2bf(o4); op[5] = f2bf(o5); op[6] = f2bf(o6); op[7] = f2bf(o7);
    } else {
        float o0 = acc0 * invd + bp[0], o1 = acc1 * invd + bp[1];
        if (MODE == 0) { o0 = fmaxf(o0, 0.f); o1 = fmaxf(o1, 0.f); }
        op[0] = f2bf(o0); op[1] = f2bf(o1);
    }
}

// ---------------- MFMA risk head: sigmoid(relu(H3@Ws1+bs1)@Ws2+bs2) ----------------
__global__ __launch_bounds__(256) void head_mfma(const unsigned short* __restrict__ H3,
                                                 const unsigned short* __restrict__ W1t,
                                                 const float* __restrict__ bs1,
                                                 const float* __restrict__ Ws2,
                                                 const float* __restrict__ bs2,
                                                 float* __restrict__ out, int M) {
    __shared__ unsigned short Asl[128 * 128];  // 32 KB
    __shared__ unsigned short Bsl[64 * 128];   // 16 KB
    const int tid = threadIdx.x, lane = tid & 63, wave = tid >> 6;
    const int q = lane >> 4, l16 = lane & 15;
    const int rowBase = blockIdx.x * 128;
    const int r0 = tid >> 4;        // 0..15
    const int cg = (tid & 15) ^ (r0 & 7);

#pragma unroll
    for (int it = 0; it < 8; it++) {
        int s = it * 256 + tid;
        int r = it * 16 + r0;
        int ga = rowBase + r; if (ga >= M) ga = M - 1;
        const unsigned short* gp = H3 + (size_t)ga * 128 + cg * 8;
        gld16(gp, &Asl[(size_t)s * 8]);
    }
#pragma unroll
    for (int it = 0; it < 4; it++) {
        int s = it * 256 + tid;
        int r = it * 16 + r0;
        const unsigned short* gp = W1t + (size_t)r * 128 + cg * 8;
        gld16(gp, &Bsl[(size_t)s * 8]);
    }
    __syncthreads();

    const int wm = wave * 32;
    f32x4 acc[2][4] = {};
#pragma unroll
    for (int kh = 0; kh < 4; kh++) {
        bf16x8 af[2], bfv[4];
#pragma unroll
        for (int mi = 0; mi < 2; mi++) {
            int row = wm + mi * 16 + l16;
            int ch = (kh * 4 + q) ^ (row & 7);
            af[mi] = *reinterpret_cast<const bf16x8*>(&Asl[row * 128 + ch * 8]);
        }
#pragma unroll
        for (int ni = 0; ni < 4; ni++) {
            int row = ni * 16 + l16;
            int ch = (kh * 4 + q) ^ (row & 7);
            bfv[ni] = *reinterpret_cast<const bf16x8*>(&Bsl[row * 128 + ch * 8]);
        }
#pragma unroll
        for (int mi = 0; mi < 2; mi++)
#pragma unroll
            for (int ni = 0; ni < 4; ni++)
                acc[mi][ni] = __builtin_amdgcn_mfma_f32_16x16x32_bf16(af[mi], bfv[ni], acc[mi][ni], 0, 0, 0);
    }
    __syncthreads();

    float b1v[4], w2v[4];
#pragma unroll
    for (int ni = 0; ni < 4; ni++) {
        int cI = ni * 16 + l16;
        b1v[ni] = bs1[cI];
        w2v[ni] = Ws2[cI];
    }
    float* red = reinterpret_cast<float*>(Bsl);
#pragma unroll
    for (int mi = 0; mi < 2; mi++) {
#pragma unroll
        for (int r = 0; r < 4; r++) {
            int lrow = wm + mi * 16 + q * 4 + r;
            float p = 0.f;
#pragma unroll
            for (int ni = 0; ni < 4; ni++)
                p += fmaxf(acc[mi][ni][r] + b1v[ni], 0.f) * w2v[ni];
#pragma unroll
            for (int d = 1; d < 16; d <<= 1) p += __shfl_xor(p, d);
            if (l16 == 0) red[lrow] = p;
        }
    }
    __syncthreads();
    if (tid < 128) {
        int g = rowBase + tid;
        if (g < M) out[g] = 1.f / (1.f + __expf(-(red[tid] + bs2[0])));
    }
}

// ---------------- launch ----------------
extern "C" void kernel_launch(void* const* d_in, const int* in_sizes, int n_in,
                              void* d_out, int out_size, void* d_ws, size_t ws_size,
                              hipStream_t stream) {
    const float* x   = (const float*)d_in[0];
    const int*   ei  = (const int*)d_in[1];
    const float* W1  = (const float*)d_in[2];
    const float* as1 = (const float*)d_in[3];
    const float* ad1 = (const float*)d_in[4];
    const float* b1  = (const float*)d_in[5];
    const float* W2  = (const float*)d_in[6];
    const float* as2 = (const float*)d_in[7];
    const float* ad2 = (const float*)d_in[8];
    const float* b2  = (const float*)d_in[9];
    const float* W3  = (const float*)d_in[10];
    const float* as3 = (const float*)d_in[11];
    const float* ad3 = (const float*)d_in[12];
    const float* b3  = (const float*)d_in[13];
    const float* Ws1 = (const float*)d_in[14];
    const float* bs1 = (const float*)d_in[15];
    const float* Ws2 = (const float*)d_in[16];
    const float* bs2 = (const float*)d_in[17];

    const int N = out_size;            // 20000
    const int E = in_sizes[1] / 2;     // 160000
    const int D = in_sizes[0] / N;     // 768
    const int HC = 512, H = 4, C = 128;
    const int Etot = E + N;

    char* p = (char*)d_ws;
    auto alloc = [&](size_t bytes) -> void* {
        void* q = (void*)p;
        p += (bytes + 255) & ~(size_t)255;
        return q;
    };
    // --- zeroed region (cursor only) ---
    char*  zbeg   = p;
    int*   cursor = (int*)alloc((size_t)N * 4);
    char*  zend   = p;
    // --- rest ---
    float* alS1   = (float*)alloc((size_t)N * H * 4);
    float* alD1   = (float*)alloc((size_t)N * H * 4);
    float* alS2   = (float*)alloc((size_t)N * H * 4);
    float* alD2   = (float*)alloc((size_t)N * H * 4);
    float* alS3   = (float*)alloc((size_t)N * 4);
    float* alD3   = (float*)alloc((size_t)N * 4);
    int*   csr    = (int*)alloc((size_t)N * MAXDEG * 4);
    unsigned short* hbuf = (unsigned short*)alloc((size_t)N * HC * 2);
    unsigned short* h3bf = (unsigned short*)alloc((size_t)N * C * 2);
    unsigned short* obf  = (unsigned short*)alloc((size_t)N * HC * 2);
    unsigned short* xbf  = (unsigned short*)alloc((size_t)N * D * 2);
    unsigned short* W1t  = (unsigned short*)alloc((size_t)D * HC * 2);
    unsigned short* W2t  = (unsigned short*)alloc((size_t)HC * HC * 2);
    unsigned short* W3t  = (unsigned short*)alloc((size_t)HC * C * 2);
    unsigned short* Ws1t = (unsigned short*)alloc((size_t)C * 64 * 2);

    hipMemsetAsync(zbeg, 0, (size_t)(zend - zbeg), stream);

    // ---- fused preprocessing (x-cast + transposes + padded-CSR scatter) ----
    {
        int n4 = N * D / 4;
        int c0 = (n4 + 255) / 256;
        int c1 = (D * HC + 255) / 256;
        int c2 = (HC * HC + 255) / 256;
        int c3 = (HC * C + 255) / 256;
        int c4 = (128 * 64 + 255) / 256;
        int c5 = (Etot + 255) / 256;
        int total = c0 + c1 + c2 + c3 + c4 + c5;
        preproc_kernel<<<total, 256, 0, stream>>>(
            x, xbf, n4, W1, W1t, W2, W2t, W3, W3t, Ws1, Ws1t,
            ei, E, N, cursor, csr, c0, c1, c2, c3, c4, D, HC, C);
    }

    int node_blocks = (N + 3) / 4;          // one wave per node
    int rowTiles128 = (N + 127) / 128;      // 157
    int rowTiles64  = (N + 63) / 64;        // 313
    int headTiles   = (N + 127) / 128;      // 157

    // ---- layer 1 ----
    gemm_big<4><<<rowTiles128 * 2, 512, 0, stream>>>(
        xbf, W1t, hbuf, N, HC, D, rowTiles128, as1, ad1, alS1, alD1);
    gat_aggregate<4, 128, 0><<<node_blocks, 256, 0, stream>>>(
        hbuf, alS1, alD1, cursor, csr, b1, obf, N);

    // ---- layer 2 ----
    gemm_big<4><<<rowTiles128 * 2, 512, 0, stream>>>(
        obf, W2t, hbuf, N, HC, HC, rowTiles128, as2, ad2, alS2, alD2);
    gat_aggregate<4, 128, 0><<<node_blocks, 256, 0, stream>>>(
        hbuf, alS2, alD2, cursor, csr, b2, obf, N);

    // ---- layer 3 (H=1) ----
    gemm_l3<<<rowTiles64, 256, 0, stream>>>(
        obf, W3t, hbuf, N, HC, as3, ad3, alS3, alD3);
    gat_aggregate<1, 128, 2><<<node_blocks, 256, 0, stream>>>(
        hbuf, alS3, alD3, cursor, csr, b3, h3bf, N);

    // ---- MFMA risk head ----
    head_mfma<<<headTiles, 256, 0, stream>>>(h3bf, Ws1t, bs1, Ws2, bs2, (float*)d_out, N);
}